// Round 15
// baseline (171.247 us; speedup 1.0000x reference)
//
#include <hip/hip_runtime.h>

typedef __attribute__((ext_vector_type(8))) __bf16 bf16x8;
typedef __attribute__((ext_vector_type(4))) float f32x4;
typedef __attribute__((ext_vector_type(16))) float f32x16;
typedef __attribute__((ext_vector_type(4))) unsigned int u32x4;
typedef __attribute__((ext_vector_type(8))) int i32x8;
typedef unsigned char u8;

#define DEV static __device__ __forceinline__

constexpr int B_ = 4, S_ = 2048, H_ = 8;
constexpr float C_LOG = 0.08838834764831845f * 1.4426950408889634f / 1024.0f;

// workspace layout (bytes)
constexpr size_t WS_Q2   = 0;                                  // fp8 [B,H,S,256] (q|qp)*32
constexpr size_t WS_K2   = WS_Q2  + (size_t)B_*H_*S_*256;      // fp8 [B,H,S,256] (k|kp)*32
constexpr size_t WS_VT   = WS_K2  + (size_t)B_*H_*S_*256;      // fp8 [B,H,128,S] (V^T)*16
constexpr size_t WS_CTX  = WS_VT  + (size_t)B_*H_*S_*128;      // bf16 [B,S,1024] raw half A
constexpr size_t WS_CTXB = WS_CTX + (size_t)B_*S_*1024*2;      // bf16 [B,S,1024] raw half B
constexpr size_t WS_WBF  = WS_CTXB+ (size_t)B_*S_*1024*2;      // bf16 5 x fragment-major
constexpr size_t WS_QLIN = WS_WBF + (size_t)5*1024*128*2;      // bf16 fragment-major
constexpr size_t WS_WCMB = WS_QLIN + (size_t)128*1024*2;       // bf16 fragment-major
constexpr size_t WS_BCMB = WS_WCMB + (size_t)128*128*2;        // f32  [128]
constexpr size_t WS_XBF  = WS_BCMB + 1024;                     // bf16 5 x [8192][128]
constexpr size_t WS_ML   = WS_XBF  + (size_t)5*8192*128*2;     // f32 [2][32][2048]

DEV __bf16 f2b(float f) {
    unsigned u = __builtin_bit_cast(unsigned, f);
    unsigned r = u + 0x7fffu + ((u >> 16) & 1u);
    unsigned short h = (unsigned short)(r >> 16);
    return __builtin_bit_cast(__bf16, h);
}

// Schraudolph exp2 approximation: 1 fma + 1 cvt, +/-3% rel err
DEV float fexp2a(float x) {
    float t = fmaf(x, 8388608.f, 1065096966.f);
    int i = (int)t;
    return __builtin_bit_cast(float, i);
}

DEV unsigned pk2(float a, float b) {
    unsigned r;
    asm("v_cvt_pk_bf16_f32 %0, %1, %2" : "=v"(r) : "v"(a), "v"(b));
    return r;
}

DEV bf16x8 cvt8(f32x4 a, f32x4 b) {
    u32x4 u{pk2(a[0], a[1]), pk2(a[2], a[3]), pk2(b[0], b[1]), pk2(b[2], b[3])};
    return __builtin_bit_cast(bf16x8, u);
}

DEV unsigned pkf8(float a, float b) {
    return (unsigned)__builtin_amdgcn_cvt_pk_fp8_f32(a, b, 0, false);
}
DEV unsigned pkf8h(unsigned old, float a, float b) {
    return (unsigned)__builtin_amdgcn_cvt_pk_fp8_f32(a, b, (int)old, true);
}
DEV u8 f2f8(float a) { return (u8)(pkf8(a, a) & 0xffu); }

DEV i32x8 ld32_8al(const u8* p) {   // 32B from 8B-aligned LDS/global (4 x b64)
    long a = *(const long*)p, b = *(const long*)(p + 8);
    long c = *(const long*)(p + 16), d = *(const long*)(p + 24);
    i32x8 r;
    r[0] = (int)a; r[1] = (int)(a >> 32);
    r[2] = (int)b; r[3] = (int)(b >> 32);
    r[4] = (int)c; r[5] = (int)(c >> 32);
    r[6] = (int)d; r[7] = (int)(d >> 32);
    return r;
}

DEV f32x16 mfma64(i32x8 a, i32x8 b, f32x16 c) {
    return __builtin_amdgcn_mfma_scale_f32_32x32x64_f8f6f4(
        a, b, c, 0, 0, 0, 0x7f7f7f7f, 0, 0x7f7f7f7f);
}

// ---- prep: weights->bf16 frag-major | W_comb | bias_comb | X->bf16 ----
__global__ __launch_bounds__(256) void k_prep(const float* wq, const float* wk,
                                              const float* wv, const float* wqp,
                                              const float* wkp, const float* qlin,
                                              const float* vlin_w, const float* wv_b,
                                              const float* vlin_b,
                                              const float* Qin, const float* Kin,
                                              const float* Vin, const float* QPin,
                                              const float* KPin, char* ws) {
    int bx = blockIdx.x, t = threadIdx.x;
    if (bx < 384) {
        __bf16* wbf = (__bf16*)(ws + WS_WBF);
        __bf16* qlb = (__bf16*)(ws + WS_QLIN);
        size_t i8 = ((size_t)bx * 256 + t) * 8;
        if (i8 < 655360) {
            int p = (int)(i8 >> 17);
            size_t e = i8 & 131071;
            int n = (int)(e >> 7), k = (int)(e & 127);
            const float* src = p == 0 ? wq : p == 1 ? wk : p == 2 ? wv : p == 3 ? wqp : wkp;
            f32x4 a = *(const f32x4*)(src + e);
            f32x4 b = *(const f32x4*)(src + e + 4);
            size_t off = (size_t)p * 131072 + ((size_t)((n >> 5) * 16 + (k >> 3))) * 256 + (n & 31) * 8;
            *(bf16x8*)(wbf + off) = cvt8(a, b);
        } else {
            size_t e = i8 - 655360;
            int n = (int)(e >> 10), k = (int)(e & 1023);
            f32x4 a = *(const f32x4*)(qlin + e);
            f32x4 b = *(const f32x4*)(qlin + e + 4);
            size_t off = ((size_t)((n >> 5) * 128 + (k >> 3))) * 256 + (n & 31) * 8;
            *(bf16x8*)(qlb + off) = cvt8(a, b);
        }
    } else if (bx < 896) {
        __bf16* wc = (__bf16*)(ws + WS_WCMB);
        int bx2 = bx - 384;
        int j = bx2 & 127, ic = bx2 >> 7;
        int il = t >> 3, part = t & 7;
        int i = ic * 32 + il;
        const float* vr = vlin_w + (size_t)i * 1024 + part * 128;
        const float* wp = wv + (size_t)part * 128 * 128 + j;
        float s = 0.f;
        #pragma unroll 4
        for (int kk = 0; kk < 32; ++kk) {
            f32x4 a = *(const f32x4*)(vr + kk * 4);
            s += a[0] * wp[(kk * 4 + 0) * 128] + a[1] * wp[(kk * 4 + 1) * 128]
               + a[2] * wp[(kk * 4 + 2) * 128] + a[3] * wp[(kk * 4 + 3) * 128];
        }
        s += __shfl_xor(s, 1);
        s += __shfl_xor(s, 2);
        s += __shfl_xor(s, 4);
        if (part == 0)
            wc[((size_t)ic * 16 + (j >> 3)) * 256 + il * 8 + (j & 7)] = f2b(s);
    } else if (bx < 900) {
        float* bc = (float*)(ws + WS_BCMB);
        int m0 = (bx - 896) * 32;
        int i = m0 + (t >> 3), part = t & 7;
        float s = 0.f;
        const float* vr = vlin_w + (size_t)i * 1024 + part * 128;
        const float* br = wv_b + part * 128;
        #pragma unroll 8
        for (int kk = 0; kk < 32; ++kk) {
            f32x4 a = *(const f32x4*)(vr + kk * 4);
            f32x4 b = *(const f32x4*)(br + kk * 4);
            s += a[0]*b[0] + a[1]*b[1] + a[2]*b[2] + a[3]*b[3];
        }
        s += __shfl_xor(s, 1);
        s += __shfl_xor(s, 2);
        s += __shfl_xor(s, 4);
        if (part == 0) bc[i] = s + vlin_b[i];
    } else {
        __bf16* xbf = (__bf16*)(ws + WS_XBF);
        size_t c = (size_t)(bx - 900) * 256 + t;
        int p = (int)(c >> 17);
        size_t e = (c & 131071) * 8;
        const float* src = p == 0 ? Qin : p == 1 ? Kin : p == 2 ? Vin : p == 3 ? QPin : KPin;
        f32x4 a = *(const f32x4*)(src + e);
        f32x4 b = *(const f32x4*)(src + e + 4);
        *(bf16x8*)(xbf + (size_t)p * 1048576 + e) = cvt8(a, b);
    }
}

// ------- projections (XCD-grouped, LDS-free, bf16 A, frag-major B) + v_out ---
__global__ __launch_bounds__(256) void k_proj(const float* bq, const float* bk,
                                              const float* bv, const float* bqp,
                                              const float* bkp, char* ws, float* out) {
    int bx = blockIdx.x, t = threadIdx.x;
    int lane = t & 63, w = t >> 6, lo = lane & 31, hi = lane >> 5;
    int xcd = bx & 7, seq = bx >> 3;
    u8* q2  = (u8*)(ws + WS_Q2);
    u8* k2  = (u8*)(ws + WS_K2);
    u8* vbT = (u8*)(ws + WS_VT);
    const __bf16* xbf = (const __bf16*)(ws + WS_XBF);
    if (seq < 320) {
        int T = (seq & ~7) + xcd;
        int nq = seq & 7;
        int p = T >> 6, mt = T & 63;
        int m0 = mt * 128 + w * 32, n0 = nq * 128;
        const float* bias = p == 0 ? bq  : p == 1 ? bk  : p == 2 ? bv  : p == 3 ? bqp  : bkp;
        const __bf16* wb = (const __bf16*)(ws + WS_WBF) + (size_t)p * 131072;
        f32x16 acc[4];
        #pragma unroll
        for (int g = 0; g < 4; ++g)
            #pragma unroll
            for (int i = 0; i < 16; ++i) acc[g][i] = 0.f;
        const __bf16* arow = xbf + (size_t)p * 1048576 + (size_t)(m0 + lo) * 128;
        #pragma unroll
        for (int ks = 0; ks < 8; ++ks) {
            bf16x8 af = *(const bf16x8*)(arow + ks * 16 + hi * 8);
            #pragma unroll
            for (int g = 0; g < 4; ++g) {
                bf16x8 bf = *(const bf16x8*)&wb[((size_t)(nq * 4 + g) * 16 + ks * 2 + hi) * 256 + lo * 8];
                acc[g] = __builtin_amdgcn_mfma_f32_32x32x16_bf16(af, bf, acc[g], 0, 0, 0);
            }
        }
        int b = m0 >> 11, s0w = m0 & 2047;
        if (p == 2) {
            #pragma unroll
            for (int g = 0; g < 4; ++g) {
                int n = n0 + g * 32 + lo, h = n >> 7, d = n & 127;
                float bn = bias[n];
                u8* dp = vbT + (((size_t)(b * H_ + h)) * 128 + d) * (size_t)S_ + s0w + 4 * hi;
                #pragma unroll
                for (int rq = 0; rq < 4; ++rq) {
                    unsigned wd = pkf8((acc[g][rq*4+0] + bn) * 16.f,
                                       (acc[g][rq*4+1] + bn) * 16.f);
                    wd = pkf8h(wd, (acc[g][rq*4+2] + bn) * 16.f,
                                   (acc[g][rq*4+3] + bn) * 16.f);
                    *(unsigned*)&dp[rq * 8] = wd;
                }
            }
        } else {
            int off = (p == 0 || p == 1) ? 0 : 128;
            u8* dstbuf = (p == 0 || p == 3) ? q2 : k2;
            #pragma unroll
            for (int g = 0; g < 4; ++g) {
                int n = n0 + g * 32 + lo, h = n >> 7, d = n & 127;
                float bn = bias[n];
                u8* dp = dstbuf + (((size_t)(b * H_ + h)) * S_ + s0w + 4 * hi) * 256 + off + d;
                #pragma unroll
                for (int r = 0; r < 16; ++r)
                    dp[((r & 3) + 8 * (r >> 2)) * 256] = f2f8((acc[g][r] + bn) * 32.f);
            }
        }
    } else {
        int T2 = (seq - 320) * 8 + xcd;
        int m0 = T2 * 128 + w * 32;
        const __bf16* wc = (const __bf16*)(ws + WS_WCMB);
        const float*  bc = (const float*)(ws + WS_BCMB);
        f32x16 acc[4];
        #pragma unroll
        for (int g = 0; g < 4; ++g)
            #pragma unroll
            for (int i = 0; i < 16; ++i) acc[g][i] = 0.f;
        const __bf16* arow = xbf + (size_t)2 * 1048576 + (size_t)(m0 + lo) * 128;
        #pragma unroll
        for (int ks = 0; ks < 8; ++ks) {
            bf16x8 af = *(const bf16x8*)(arow + ks * 16 + hi * 8);
            #pragma unroll
            for (int g = 0; g < 4; ++g) {
                bf16x8 bf = *(const bf16x8*)&wc[((size_t)g * 16 + ks * 2 + hi) * 256 + lo * 8];
                acc[g] = __builtin_amdgcn_mfma_f32_32x32x16_bf16(af, bf, acc[g], 0, 0, 0);
            }
        }
        #pragma unroll
        for (int g = 0; g < 4; ++g) {
            int n = g * 32 + lo;
            float bn = bc[n];
            float* op = out + 1048576 + (size_t)(m0 + 4 * hi) * 128 + n;
            #pragma unroll
            for (int r = 0; r < 16; ++r)
                op[((r & 3) + 8 * (r >> 2)) * 128] = acc[g][r] + bn;
        }
    }
}

// --- flash attention: fp8 K=64 scaled MFMA; fixed-max; SPLIT-K; raw ctx halves ----
__global__ __launch_bounds__(256, 2) void k_attn(char* ws) {
    __shared__ __align__(16) u8 Kb[2][16896];   // [64 rows][264B]
    __shared__ __align__(16) u8 Vt[2][9216];    // [128 rows][72B]
    const u8* q2 = (const u8*)(ws + WS_Q2);
    const u8* k2 = (const u8*)(ws + WS_K2);
    const u8* vT = (const u8*)(ws + WS_VT);

    int bx = blockIdx.x;
    int xcd = bx & 7;
    int idx = bx >> 3;                 // 0..127
    int bh = xcd * 4 + (idx >> 5);
    int rem = idx & 31;
    int qt = rem >> 1, half = rem & 1;
    int ktbase = half * 16;
    int t = threadIdx.x, lane = t & 63, w = t >> 6;
    int lo = lane & 31, hi = lane >> 5;

    const u8* k2b = k2 + (size_t)bh * S_ * 256;
    const u8* vTb = vT + (size_t)bh * 128 * S_;
    int q0 = qt * 128;
    int qrow = q0 + w * 32 + lo;

    i32x8 qf[4];
    {
        const u8* qp = q2 + ((size_t)bh * S_ + qrow) * 256 + hi * 32;
        #pragma unroll
        for (int kb = 0; kb < 4; ++kb) qf[kb] = ld32_8al(qp + kb * 64);
    }

    f32x16 ctx[4], lacc;
    #pragma unroll
    for (int i = 0; i < 4; ++i)
        #pragma unroll
        for (int j = 0; j < 16; ++j) ctx[i][j] = 0.f;
    #pragma unroll
    for (int j = 0; j < 16; ++j) lacc[j] = 0.f;

    i32x8 ones;
    #pragma unroll
    for (int j = 0; j < 8; ++j) ones[j] = 0x38383838;   // fp8 e4m3 1.0 x4

    u32x4 kA[4], kB[4];
    long vA[4], vB[4];

    auto load_k = [&](u32x4* kr, int kt) __attribute__((always_inline)) {
        const u8* src = k2b + (size_t)kt * 16384 + t * 16;
        #pragma unroll
        for (int i = 0; i < 4; ++i) kr[i] = *(const u32x4*)(src + i * 4096);
    };
    auto write_k = [&](int buf, const u32x4* kr) __attribute__((always_inline)) {
        u8* dst = &Kb[buf][(t >> 4) * 264 + (t & 15) * 16];
        #pragma unroll
        for (int i = 0; i < 4; ++i) {
            u32x4 v = kr[i];
            long lo8 = (long)(((unsigned long)v[1] << 32) | v[0]);
            long hi8 = (long)(((unsigned long)v[3] << 32) | v[2]);
            *(long*)(dst + (size_t)i * 4224) = lo8;
            *(long*)(dst + (size_t)i * 4224 + 8) = hi8;
        }
    };
    auto load_v = [&](long* vr, int kt) __attribute__((always_inline)) {
        #pragma unroll
        for (int i = 0; i < 4; ++i) {
            int d = i * 32 + (t >> 3), kb = t & 7;
            vr[i] = *(const long*)(vTb + (size_t)d * S_ + kt * 64 + kb * 8);
        }
    };
    auto write_vt = [&](int buf, const long* vr) __attribute__((always_inline)) {
        #pragma unroll
        for (int i = 0; i < 4; ++i) {
            int d = i * 32 + (t >> 3), kb = t & 7;
            *(long*)&Vt[buf][d * 72 + kb * 8] = vr[i];
        }
    };
    auto body = [&](int it, const u8* kbp, const u8* vtp,
                    u32x4* kld, long* vld, const u32x4* kwr, const long* vwr,
                    int wbuf) __attribute__((always_inline)) {
        // ---- QK^T: 8 x mfma K=64 ----
        f32x16 s0, s1;
        #pragma unroll
        for (int j = 0; j < 16; ++j) { s0[j] = 0.f; s1[j] = 0.f; }
        __builtin_amdgcn_s_setprio(1);
        #pragma unroll
        for (int kb = 0; kb < 4; ++kb) {
            i32x8 a0 = ld32_8al(&kbp[lo * 264 + kb * 64 + hi * 32]);
            i32x8 a1 = ld32_8al(&kbp[(32 + lo) * 264 + kb * 64 + hi * 32]);
            s0 = mfma64(a0, qf[kb], s0);
            s1 = mfma64(a1, qf[kb], s1);
        }
        __builtin_amdgcn_s_setprio(0);

        int it2n = it + 2 < 16 ? it + 2 : 15;
        load_k(kld, ktbase + it2n);
        load_v(vld, ktbase + it2n);

        // ---- softmax, fixed max: P = exp2(s*c + 4) ----
        #pragma unroll
        for (int j = 0; j < 16; ++j) {
            s0[j] = fexp2a(fmaf(s0[j], C_LOG, 4.0f));
            s1[j] = fexp2a(fmaf(s1[j], C_LOG, 4.0f));
        }

        // ---- P -> single K=64 fp8 B-fragment ----
        unsigned d[4], e[4];
        #pragma unroll
        for (int a = 0; a < 4; ++a) {
            d[a] = pkf8h(pkf8(s0[4*a], s0[4*a+1]), s0[4*a+2], s0[4*a+3]);
            e[a] = pkf8h(pkf8(s1[4*a], s1[4*a+1]), s1[4*a+2], s1[4*a+3]);
        }
        #pragma unroll
        for (int a = 0; a < 4; ++a)
            asm("v_permlane32_swap_b32 %0, %1" : "+v"(e[a]), "+v"(d[a]));
        i32x8 pfr;
        pfr[0] = (int)d[0]; pfr[1] = (int)e[0];
        pfr[2] = (int)d[1]; pfr[3] = (int)e[1];
        pfr[4] = (int)d[2]; pfr[5] = (int)e[2];
        pfr[6] = (int)d[3]; pfr[7] = (int)e[3];

        // ---- PV: 4 x mfma K=64 + l via ones-MFMA ----
        __builtin_amdgcn_s_setprio(1);
        #pragma unroll
        for (int ds = 0; ds < 4; ++ds) {
            i32x8 va = ld32_8al(&vtp[(ds * 32 + lo) * 72 + hi * 32]);
            ctx[ds] = mfma64(va, pfr, ctx[ds]);
        }
        lacc = mfma64(ones, pfr, lacc);
        __builtin_amdgcn_s_setprio(0);

        asm volatile("s_waitcnt vmcnt(8)" ::: "memory");
        __builtin_amdgcn_sched_barrier(0);
        write_k(wbuf, kwr);
        write_vt(wbuf, vwr);
        asm volatile("s_waitcnt lgkmcnt(0)" ::: "memory");
        __builtin_amdgcn_s_barrier();
        __builtin_amdgcn_sched_barrier(0);
    };

    // prologue
    load_k(kA, ktbase + 0);
    load_v(vA, ktbase + 0);
    load_k(kB, ktbase + 1);
    load_v(vB, ktbase + 1);
    asm volatile("s_waitcnt vmcnt(8)" ::: "memory");
    __builtin_amdgcn_sched_barrier(0);
    write_k(0, kA);
    write_vt(0, vA);
    asm volatile("s_waitcnt lgkmcnt(0)" ::: "memory");
    __builtin_amdgcn_s_barrier();
    __builtin_amdgcn_sched_barrier(0);

    for (int it2 = 0; it2 < 8; ++it2) {
        body(it2 * 2,     &Kb[0][0], &Vt[0][0], kA, vA, kB, vB, 1);
        body(it2 * 2 + 1, &Kb[1][0], &Vt[1][0], kB, vB, kA, vA, 0);
    }

    // ---- store l ----
    {
        float* ml = (float*)(ws + WS_ML);
        if (hi == 0) ml[((size_t)(half * 32 + bh)) * S_ + qrow] = lacc[0];
    }

    // ---- epilogue: RAW ctx, per-wave LDS bounce, coalesced bf16 write ----
    __bf16* ctxg = (__bf16*)(ws + (half ? WS_CTXB : WS_CTX));
    __bf16* sc = (__bf16*)&Kb[0][0] + w * 4096;
    #pragma unroll
    for (int ds = 0; ds < 4; ++ds) {
        #pragma unroll
        for (int g = 0; g < 4; ++g) {
            #pragma unroll
            for (int h2 = 0; h2 < 2; ++h2) {
                int r = g * 4 + h2 * 2;
                unsigned pv = pk2(ctx[ds][r], ctx[ds][r + 1]);
                int d = ds * 32 + (r & 3) + 8 * (r >> 2) + 4 * hi;
                *(unsigned*)&sc[lo * 128 + (((d >> 3) ^ (lo & 7)) << 3) + (d & 7)] = pv;
            }
        }
    }
    {
        int b = bh >> 3, h = bh & 7;
        int qq = lane >> 1, halfd = lane & 1;
        int srow = q0 + w * 32 + qq;
        #pragma unroll
        for (int j = 0; j < 8; ++j) {
            int d8 = halfd * 8 + j;
            bf16x8 vv = *(const bf16x8*)&sc[qq * 128 + ((d8 ^ (qq & 7)) << 3)];
            *(bf16x8*)&ctxg[((size_t)(b * S_ + srow)) * 1024 + h * 128 + d8 * 8] = vv;
        }
    }
}

// --- out = LN(((rawA+rawB)/(16(lA+lB))) @ qlin^T + qlin_b + Q); merge fused --------
__global__ __launch_bounds__(256) void k_out(const float* Qin, const float* qlin_b,
                                             const float* ln_g, const float* ln_b,
                                             char* ws, float* out) {
    __shared__ f32x16 red[3][4][64];
    int t = threadIdx.x, w = t >> 6, l64 = t & 63;
    int lo = l64 & 31, hi = l64 >> 5;
    int m0 = blockIdx.x * 32;
    const __bf16* ctxA = (const __bf16*)(ws + WS_CTX);
    const __bf16* ctxB = (const __bf16*)(ws + WS_CTXB);
    const __bf16* qlb = (const __bf16*)(ws + WS_QLIN);
    const float* ml = (const float*)(ws + WS_ML);

    // per-lane merge inv for this wave's two heads (h = 2w + (ks>>3))
    int arow_i = m0 + lo;
    int b = arow_i >> 11, s = arow_i & 2047;
    float inv0, inv1;
    {
        int bh0 = b * H_ + 2 * w, bh1 = bh0 + 1;
        float lA0 = ml[(size_t)bh0 * S_ + s], lB0 = ml[((size_t)(32 + bh0)) * S_ + s];
        float lA1 = ml[(size_t)bh1 * S_ + s], lB1 = ml[((size_t)(32 + bh1)) * S_ + s];
        inv0 = 1.f / (16.f * (lA0 + lB0));
        inv1 = 1.f / (16.f * (lA1 + lB1));
    }

    f32x16 acc[4];
    #pragma unroll
    for (int g = 0; g < 4; ++g)
        #pragma unroll
        for (int i = 0; i < 16; ++i) acc[g][i] = 0.f;
    const __bf16* arowA = ctxA + (size_t)arow_i * 1024 + w * 256;
    const __bf16* arowB = ctxB + (size_t)arow_i * 1024 + w * 256;
    #pragma unroll
    for (int ks = 0; ks < 16; ++ks) {
        int kb = ks * 16 + hi * 8;
        float invs = (ks < 8) ? inv0 : inv1;
        bf16x8 a8 = *(const bf16x8*)(arowA + kb);
        bf16x8 b8 = *(const bf16x8*)(arowB + kb);
        u32x4 u;
        #pragma unroll
        for (int q = 0; q < 4; ++q) {
            float x0 = ((float)a8[2*q]   + (float)b8[2*q])   * invs;
            float x1 = ((float)a8[2*q+1] + (float)b8[2*q+1]) * invs;
            u[q] = pk2(x0, x1);
        }
        bf16x8 af = __builtin_bit_cast(bf16x8, u);
        int ksg = w * 16 + ks;
        #pragma unroll
        for (int g = 0; g < 4; ++g) {
            bf16x8 bf = *(const bf16x8*)&qlb[((size_t)g * 128 + ksg * 2 + hi) * 256 + lo * 8];
            acc[g] = __builtin_amdgcn_mfma_f32_32x32x16_bf16(af, bf, acc[g], 0, 0, 0);
        }
    }
    if (w > 0) {
        #pragma unroll
        for (int g = 0; g < 4; ++g) red[w - 1][g][l64] = acc[g];
    }
    __syncthreads();
    if (w > 0) return;
    #pragma unroll
    for (int v = 0; v < 3; ++v)
        #pragma unroll
        for (int g = 0; g < 4; ++g) {
            f32x16 o = red[v][g][l64];
            #pragma unroll
            for (int i = 0; i < 16; ++i) acc[g][i] += o[i];
        }
    float gb[4], bb[4], qb[4];
    #pragma unroll
    for (int g = 0; g < 4; ++g) {
        int n = g * 32 + lo;
        gb[g] = ln_g[n]; bb[g] = ln_b[n]; qb[g] = qlin_b[n];
    }
    const float* qp = Qin + (size_t)(m0 + 4 * hi) * 128;
    float* op = out + (size_t)(m0 + 4 * hi) * 128;
    #pragma unroll
    for (int r = 0; r < 16; ++r) {
        int ro = ((r & 3) + 8 * (r >> 2)) * 128;
        float x[4];
        float sum = 0.f;
        #pragma unroll
        for (int g = 0; g < 4; ++g) {
            x[g] = acc[g][r] + qb[g] + qp[ro + g * 32 + lo];
            sum += x[g];
        }
        sum += __shfl_xor(sum, 1);
        sum += __shfl_xor(sum, 2);
        sum += __shfl_xor(sum, 4);
        sum += __shfl_xor(sum, 8);
        sum += __shfl_xor(sum, 16);
        float mean = sum * (1.f / 128.f);
        float sq = 0.f;
        #pragma unroll
        for (int g = 0; g < 4; ++g) {
            float d = x[g] - mean;
            sq += d * d;
        }
        sq += __shfl_xor(sq, 1);
        sq += __shfl_xor(sq, 2);
        sq += __shfl_xor(sq, 4);
        sq += __shfl_xor(sq, 8);
        sq += __shfl_xor(sq, 16);
        float rstd = rsqrtf(sq * (1.f / 128.f) + 1e-5f);
        #pragma unroll
        for (int g = 0; g < 4; ++g)
            op[ro + g * 32 + lo] = (x[g] - mean) * rstd * gb[g] + bb[g];
    }
}

extern "C" void kernel_launch(void* const* d_in, const int* in_sizes, int n_in,
                              void* d_out, int out_size, void* d_ws, size_t ws_size,
                              hipStream_t stream) {
    (void)in_sizes; (void)n_in; (void)out_size; (void)ws_size;
    const float* Q    = (const float*)d_in[0];
    const float* K    = (const float*)d_in[1];
    const float* V    = (const float*)d_in[2];
    const float* QP   = (const float*)d_in[3];
    const float* KP   = (const float*)d_in[4];
    const float* WQw  = (const float*)d_in[6];
    const float* WQb  = (const float*)d_in[7];
    const float* WKw  = (const float*)d_in[8];
    const float* WKb  = (const float*)d_in[9];
    const float* WVw  = (const float*)d_in[10];
    const float* WVb  = (const float*)d_in[11];
    const float* WQPw = (const float*)d_in[12];
    const float* WQPb = (const float*)d_in[13];
    const float* WKPw = (const float*)d_in[14];
    const float* WKPb = (const float*)d_in[15];
    const float* qlw  = (const float*)d_in[18];
    const float* qlb  = (const float*)d_in[19];
    const float* vlw  = (const float*)d_in[20];
    const float* vlb  = (const float*)d_in[21];
    const float* lng  = (const float*)d_in[22];
    const float* lnb  = (const float*)d_in[23];
    char* ws = (char*)d_ws;
    float* out = (float*)d_out;

    k_prep<<<3460, 256, 0, stream>>>(WQw, WKw, WVw, WQPw, WKPw, qlw, vlw, WVb, vlb,
                                     Q, K, V, QP, KP, ws);
    k_proj<<<2624, 256, 0, stream>>>(WQb, WKb, WVb, WQPb, WKPb, ws, out);
    k_attn<<<1024, 256, 0, stream>>>(ws);
    k_out<<<256, 256, 0, stream>>>(Q, qlb, lng, lnb, ws, out);
}

// Round 16
// 154.603 us; speedup vs baseline: 1.1077x; 1.1077x over previous
//
#include <hip/hip_runtime.h>

typedef __attribute__((ext_vector_type(8))) __bf16 bf16x8;
typedef __attribute__((ext_vector_type(4))) float f32x4;
typedef __attribute__((ext_vector_type(16))) float f32x16;
typedef __attribute__((ext_vector_type(4))) unsigned int u32x4;
typedef __attribute__((ext_vector_type(8))) int i32x8;
typedef unsigned char u8;

#define DEV static __device__ __forceinline__

constexpr int B_ = 4, S_ = 2048, H_ = 8;
constexpr float C_LOG = 0.08838834764831845f * 1.4426950408889634f / 1024.0f;

// workspace layout (bytes)
constexpr size_t WS_Q2   = 0;                                  // fp8 [B,H,S,256] (q|qp)*32
constexpr size_t WS_K2   = WS_Q2  + (size_t)B_*H_*S_*256;      // fp8 [B,H,S,256] (k|kp)*32
constexpr size_t WS_VT   = WS_K2  + (size_t)B_*H_*S_*256;      // fp8 [B,H,128,S] (V^T)*16
constexpr size_t WS_CTX  = WS_VT  + (size_t)B_*H_*S_*128;      // bf16 [B,S,1024]
constexpr size_t WS_WBF  = WS_CTX + (size_t)B_*S_*1024*2;      // bf16 5 x fragment-major
constexpr size_t WS_QLIN = WS_WBF + (size_t)5*1024*128*2;      // bf16 fragment-major
constexpr size_t WS_WCMB = WS_QLIN + (size_t)128*1024*2;       // bf16 fragment-major
constexpr size_t WS_BCMB = WS_WCMB + (size_t)128*128*2;        // f32  [128]
constexpr size_t WS_XBF  = WS_BCMB + 1024;                     // bf16 5 x [8192][128]

DEV __bf16 f2b(float f) {
    unsigned u = __builtin_bit_cast(unsigned, f);
    unsigned r = u + 0x7fffu + ((u >> 16) & 1u);
    unsigned short h = (unsigned short)(r >> 16);
    return __builtin_bit_cast(__bf16, h);
}

// Schraudolph exp2 approximation: 1 fma + 1 cvt, +/-3% rel err, valid x in (-120, 120)
DEV float fexp2a(float x) {
    float t = fmaf(x, 8388608.f, 1065096966.f);
    int i = (int)t;
    return __builtin_bit_cast(float, i);
}

DEV unsigned pk2(float a, float b) {
    unsigned r;
    asm("v_cvt_pk_bf16_f32 %0, %1, %2" : "=v"(r) : "v"(a), "v"(b));
    return r;
}

DEV bf16x8 cvt8(f32x4 a, f32x4 b) {
    u32x4 u{pk2(a[0], a[1]), pk2(a[2], a[3]), pk2(b[0], b[1]), pk2(b[2], b[3])};
    return __builtin_bit_cast(bf16x8, u);
}

DEV unsigned pkf8(float a, float b) {
    return (unsigned)__builtin_amdgcn_cvt_pk_fp8_f32(a, b, 0, false);
}
DEV unsigned pkf8h(unsigned old, float a, float b) {
    return (unsigned)__builtin_amdgcn_cvt_pk_fp8_f32(a, b, (int)old, true);
}
DEV u8 f2f8(float a) { return (u8)(pkf8(a, a) & 0xffu); }

DEV i32x8 ld32_8al(const u8* p) {   // 32B from 8B-aligned LDS/global (4 x b64)
    long a = *(const long*)p, b = *(const long*)(p + 8);
    long c = *(const long*)(p + 16), d = *(const long*)(p + 24);
    i32x8 r;
    r[0] = (int)a; r[1] = (int)(a >> 32);
    r[2] = (int)b; r[3] = (int)(b >> 32);
    r[4] = (int)c; r[5] = (int)(c >> 32);
    r[6] = (int)d; r[7] = (int)(d >> 32);
    return r;
}

DEV f32x16 mfma64(i32x8 a, i32x8 b, f32x16 c) {
    return __builtin_amdgcn_mfma_scale_f32_32x32x64_f8f6f4(
        a, b, c, 0, 0, 0, 0x7f7f7f7f, 0, 0x7f7f7f7f);
}

// ---- prep: weights->bf16 frag-major | W_comb | bias_comb | X->bf16 ----
__global__ __launch_bounds__(256) void k_prep(const float* wq, const float* wk,
                                              const float* wv, const float* wqp,
                                              const float* wkp, const float* qlin,
                                              const float* vlin_w, const float* wv_b,
                                              const float* vlin_b,
                                              const float* Qin, const float* Kin,
                                              const float* Vin, const float* QPin,
                                              const float* KPin, char* ws) {
    int bx = blockIdx.x, t = threadIdx.x;
    if (bx < 384) {
        __bf16* wbf = (__bf16*)(ws + WS_WBF);
        __bf16* qlb = (__bf16*)(ws + WS_QLIN);
        size_t i8 = ((size_t)bx * 256 + t) * 8;
        if (i8 < 655360) {
            int p = (int)(i8 >> 17);
            size_t e = i8 & 131071;
            int n = (int)(e >> 7), k = (int)(e & 127);
            const float* src = p == 0 ? wq : p == 1 ? wk : p == 2 ? wv : p == 3 ? wqp : wkp;
            f32x4 a = *(const f32x4*)(src + e);
            f32x4 b = *(const f32x4*)(src + e + 4);
            size_t off = (size_t)p * 131072 + ((size_t)((n >> 5) * 16 + (k >> 3))) * 256 + (n & 31) * 8;
            *(bf16x8*)(wbf + off) = cvt8(a, b);
        } else {
            size_t e = i8 - 655360;
            int n = (int)(e >> 10), k = (int)(e & 1023);
            f32x4 a = *(const f32x4*)(qlin + e);
            f32x4 b = *(const f32x4*)(qlin + e + 4);
            size_t off = ((size_t)((n >> 5) * 128 + (k >> 3))) * 256 + (n & 31) * 8;
            *(bf16x8*)(qlb + off) = cvt8(a, b);
        }
    } else if (bx < 896) {
        __bf16* wc = (__bf16*)(ws + WS_WCMB);
        int bx2 = bx - 384;
        int j = bx2 & 127, ic = bx2 >> 7;
        int il = t >> 3, part = t & 7;
        int i = ic * 32 + il;
        const float* vr = vlin_w + (size_t)i * 1024 + part * 128;
        const float* wp = wv + (size_t)part * 128 * 128 + j;
        float s = 0.f;
        #pragma unroll 4
        for (int kk = 0; kk < 32; ++kk) {
            f32x4 a = *(const f32x4*)(vr + kk * 4);
            s += a[0] * wp[(kk * 4 + 0) * 128] + a[1] * wp[(kk * 4 + 1) * 128]
               + a[2] * wp[(kk * 4 + 2) * 128] + a[3] * wp[(kk * 4 + 3) * 128];
        }
        s += __shfl_xor(s, 1);
        s += __shfl_xor(s, 2);
        s += __shfl_xor(s, 4);
        if (part == 0)
            wc[((size_t)ic * 16 + (j >> 3)) * 256 + il * 8 + (j & 7)] = f2b(s);
    } else if (bx < 900) {
        float* bc = (float*)(ws + WS_BCMB);
        int m0 = (bx - 896) * 32;
        int i = m0 + (t >> 3), part = t & 7;
        float s = 0.f;
        const float* vr = vlin_w + (size_t)i * 1024 + part * 128;
        const float* br = wv_b + part * 128;
        #pragma unroll 8
        for (int kk = 0; kk < 32; ++kk) {
            f32x4 a = *(const f32x4*)(vr + kk * 4);
            f32x4 b = *(const f32x4*)(br + kk * 4);
            s += a[0]*b[0] + a[1]*b[1] + a[2]*b[2] + a[3]*b[3];
        }
        s += __shfl_xor(s, 1);
        s += __shfl_xor(s, 2);
        s += __shfl_xor(s, 4);
        if (part == 0) bc[i] = s + vlin_b[i];
    } else {
        // X inputs -> bf16 [p][8192][128]
        __bf16* xbf = (__bf16*)(ws + WS_XBF);
        size_t c = (size_t)(bx - 900) * 256 + t;
        int p = (int)(c >> 17);
        size_t e = (c & 131071) * 8;
        const float* src = p == 0 ? Qin : p == 1 ? Kin : p == 2 ? Vin : p == 3 ? QPin : KPin;
        f32x4 a = *(const f32x4*)(src + e);
        f32x4 b = *(const f32x4*)(src + e + 4);
        *(bf16x8*)(xbf + (size_t)p * 1048576 + e) = cvt8(a, b);
    }
}

// ------- projections (XCD-grouped, LDS-free, bf16 A, frag-major B) + v_out ---
__global__ __launch_bounds__(256) void k_proj(const float* bq, const float* bk,
                                              const float* bv, const float* bqp,
                                              const float* bkp, char* ws, float* out) {
    int bx = blockIdx.x, t = threadIdx.x;
    int lane = t & 63, w = t >> 6, lo = lane & 31, hi = lane >> 5;
    int xcd = bx & 7, seq = bx >> 3;
    u8* q2  = (u8*)(ws + WS_Q2);
    u8* k2  = (u8*)(ws + WS_K2);
    u8* vbT = (u8*)(ws + WS_VT);
    const __bf16* xbf = (const __bf16*)(ws + WS_XBF);
    if (seq < 320) {
        int T = (seq & ~7) + xcd;
        int nq = seq & 7;
        int p = T >> 6, mt = T & 63;
        int m0 = mt * 128 + w * 32, n0 = nq * 128;
        const float* bias = p == 0 ? bq  : p == 1 ? bk  : p == 2 ? bv  : p == 3 ? bqp  : bkp;
        const __bf16* wb = (const __bf16*)(ws + WS_WBF) + (size_t)p * 131072;
        f32x16 acc[4];
        #pragma unroll
        for (int g = 0; g < 4; ++g)
            #pragma unroll
            for (int i = 0; i < 16; ++i) acc[g][i] = 0.f;
        const __bf16* arow = xbf + (size_t)p * 1048576 + (size_t)(m0 + lo) * 128;
        #pragma unroll
        for (int ks = 0; ks < 8; ++ks) {
            bf16x8 af = *(const bf16x8*)(arow + ks * 16 + hi * 8);
            #pragma unroll
            for (int g = 0; g < 4; ++g) {
                bf16x8 bf = *(const bf16x8*)&wb[((size_t)(nq * 4 + g) * 16 + ks * 2 + hi) * 256 + lo * 8];
                acc[g] = __builtin_amdgcn_mfma_f32_32x32x16_bf16(af, bf, acc[g], 0, 0, 0);
            }
        }
        int b = m0 >> 11, s0w = m0 & 2047;
        if (p == 2) {
            #pragma unroll
            for (int g = 0; g < 4; ++g) {
                int n = n0 + g * 32 + lo, h = n >> 7, d = n & 127;
                float bn = bias[n];
                u8* dp = vbT + (((size_t)(b * H_ + h)) * 128 + d) * (size_t)S_ + s0w + 4 * hi;
                #pragma unroll
                for (int rq = 0; rq < 4; ++rq) {
                    unsigned wd = pkf8((acc[g][rq*4+0] + bn) * 16.f,
                                       (acc[g][rq*4+1] + bn) * 16.f);
                    wd = pkf8h(wd, (acc[g][rq*4+2] + bn) * 16.f,
                                   (acc[g][rq*4+3] + bn) * 16.f);
                    *(unsigned*)&dp[rq * 8] = wd;
                }
            }
        } else {
            int off = (p == 0 || p == 1) ? 0 : 128;
            u8* dstbuf = (p == 0 || p == 3) ? q2 : k2;
            #pragma unroll
            for (int g = 0; g < 4; ++g) {
                int n = n0 + g * 32 + lo, h = n >> 7, d = n & 127;
                float bn = bias[n];
                u8* dp = dstbuf + (((size_t)(b * H_ + h)) * S_ + s0w + 4 * hi) * 256 + off + d;
                #pragma unroll
                for (int r = 0; r < 16; ++r)
                    dp[((r & 3) + 8 * (r >> 2)) * 256] = f2f8((acc[g][r] + bn) * 32.f);
            }
        }
    } else {
        int T2 = (seq - 320) * 8 + xcd;
        int m0 = T2 * 128 + w * 32;
        const __bf16* wc = (const __bf16*)(ws + WS_WCMB);
        const float*  bc = (const float*)(ws + WS_BCMB);
        f32x16 acc[4];
        #pragma unroll
        for (int g = 0; g < 4; ++g)
            #pragma unroll
            for (int i = 0; i < 16; ++i) acc[g][i] = 0.f;
        const __bf16* arow = xbf + (size_t)2 * 1048576 + (size_t)(m0 + lo) * 128;
        #pragma unroll
        for (int ks = 0; ks < 8; ++ks) {
            bf16x8 af = *(const bf16x8*)(arow + ks * 16 + hi * 8);
            #pragma unroll
            for (int g = 0; g < 4; ++g) {
                bf16x8 bf = *(const bf16x8*)&wc[((size_t)g * 16 + ks * 2 + hi) * 256 + lo * 8];
                acc[g] = __builtin_amdgcn_mfma_f32_32x32x16_bf16(af, bf, acc[g], 0, 0, 0);
            }
        }
        #pragma unroll
        for (int g = 0; g < 4; ++g) {
            int n = g * 32 + lo;
            float bn = bc[n];
            float* op = out + 1048576 + (size_t)(m0 + 4 * hi) * 128 + n;
            #pragma unroll
            for (int r = 0; r < 16; ++r)
                op[((r & 3) + 8 * (r >> 2)) * 128] = acc[g][r] + bn;
        }
    }
}

// --- flash attention: fp8 K=64 scaled MFMA; FIXED-max softmax; l via ones-MFMA ----
__global__ __launch_bounds__(256, 2) void k_attn(char* ws) {
    __shared__ __align__(16) u8 Kb[2][16896];   // [64 rows][264B]
    __shared__ __align__(16) u8 Vt[2][9216];    // [128 rows][72B]
    const u8* q2 = (const u8*)(ws + WS_Q2);
    const u8* k2 = (const u8*)(ws + WS_K2);
    const u8* vT = (const u8*)(ws + WS_VT);
    __bf16* ctxg = (__bf16*)(ws + WS_CTX);

    int bx = blockIdx.x;
    int xcd = bx & 7;
    int idx = bx >> 3;
    int bh = xcd * 4 + (idx >> 4);
    int qt = idx & 15;
    int t = threadIdx.x, lane = t & 63, w = t >> 6;
    int lo = lane & 31, hi = lane >> 5;

    const u8* k2b = k2 + (size_t)bh * S_ * 256;
    const u8* vTb = vT + (size_t)bh * 128 * S_;
    int q0 = qt * 128;
    int qrow = q0 + w * 32 + lo;

    i32x8 qf[4];
    {
        const u8* qp = q2 + ((size_t)bh * S_ + qrow) * 256 + hi * 32;
        #pragma unroll
        for (int kb = 0; kb < 4; ++kb) qf[kb] = ld32_8al(qp + kb * 64);
    }

    f32x16 ctx[4], lacc;
    #pragma unroll
    for (int i = 0; i < 4; ++i)
        #pragma unroll
        for (int j = 0; j < 16; ++j) ctx[i][j] = 0.f;
    #pragma unroll
    for (int j = 0; j < 16; ++j) lacc[j] = 0.f;

    i32x8 ones;
    #pragma unroll
    for (int j = 0; j < 8; ++j) ones[j] = 0x38383838;   // fp8 e4m3 1.0 x4

    u32x4 kA[4], kB[4];
    long vA[4], vB[4];

    auto load_k = [&](u32x4* kr, int kt) __attribute__((always_inline)) {
        const u8* src = k2b + (size_t)kt * 16384 + t * 16;
        #pragma unroll
        for (int i = 0; i < 4; ++i) kr[i] = *(const u32x4*)(src + i * 4096);
    };
    auto write_k = [&](int buf, const u32x4* kr) __attribute__((always_inline)) {
        u8* dst = &Kb[buf][(t >> 4) * 264 + (t & 15) * 16];
        #pragma unroll
        for (int i = 0; i < 4; ++i) {
            u32x4 v = kr[i];
            long lo8 = (long)(((unsigned long)v[1] << 32) | v[0]);
            long hi8 = (long)(((unsigned long)v[3] << 32) | v[2]);
            *(long*)(dst + (size_t)i * 4224) = lo8;
            *(long*)(dst + (size_t)i * 4224 + 8) = hi8;
        }
    };
    auto load_v = [&](long* vr, int kt) __attribute__((always_inline)) {
        #pragma unroll
        for (int i = 0; i < 4; ++i) {
            int d = i * 32 + (t >> 3), kb = t & 7;
            vr[i] = *(const long*)(vTb + (size_t)d * S_ + kt * 64 + kb * 8);
        }
    };
    auto write_vt = [&](int buf, const long* vr) __attribute__((always_inline)) {
        #pragma unroll
        for (int i = 0; i < 4; ++i) {
            int d = i * 32 + (t >> 3), kb = t & 7;
            *(long*)&Vt[buf][d * 72 + kb * 8] = vr[i];
        }
    };
    auto body = [&](int it, const u8* kbp, const u8* vtp,
                    u32x4* kld, long* vld, const u32x4* kwr, const long* vwr,
                    int wbuf) __attribute__((always_inline)) {
        // ---- QK^T: 8 x mfma K=64 ----
        f32x16 s0, s1;
        #pragma unroll
        for (int j = 0; j < 16; ++j) { s0[j] = 0.f; s1[j] = 0.f; }
        __builtin_amdgcn_s_setprio(1);
        #pragma unroll
        for (int kb = 0; kb < 4; ++kb) {
            i32x8 a0 = ld32_8al(&kbp[lo * 264 + kb * 64 + hi * 32]);
            i32x8 a1 = ld32_8al(&kbp[(32 + lo) * 264 + kb * 64 + hi * 32]);
            s0 = mfma64(a0, qf[kb], s0);
            s1 = mfma64(a1, qf[kb], s1);
        }
        __builtin_amdgcn_s_setprio(0);

        int kt2 = it + 2 < 32 ? it + 2 : 31;
        load_k(kld, kt2);
        load_v(vld, kt2);

        // ---- softmax, FIXED max (scores are ~185 sigma below fp8 overflow) ----
        #pragma unroll
        for (int j = 0; j < 16; ++j) {
            s0[j] = fexp2a(fmaf(s0[j], C_LOG, 4.0f));
            s1[j] = fexp2a(fmaf(s1[j], C_LOG, 4.0f));
        }

        // ---- P -> single K=64 fp8 B-fragment ----
        unsigned d[4], e[4];
        #pragma unroll
        for (int a = 0; a < 4; ++a) {
            d[a] = pkf8h(pkf8(s0[4*a], s0[4*a+1]), s0[4*a+2], s0[4*a+3]);
            e[a] = pkf8h(pkf8(s1[4*a], s1[4*a+1]), s1[4*a+2], s1[4*a+3]);
        }
        #pragma unroll
        for (int a = 0; a < 4; ++a)
            asm("v_permlane32_swap_b32 %0, %1" : "+v"(e[a]), "+v"(d[a]));
        i32x8 pfr;
        pfr[0] = (int)d[0]; pfr[1] = (int)e[0];
        pfr[2] = (int)d[1]; pfr[3] = (int)e[1];
        pfr[4] = (int)d[2]; pfr[5] = (int)e[2];
        pfr[6] = (int)d[3]; pfr[7] = (int)e[3];

        // ---- PV: 4 x mfma K=64, + l accumulation via ones-row MFMA ----
        __builtin_amdgcn_s_setprio(1);
        #pragma unroll
        for (int ds = 0; ds < 4; ++ds) {
            i32x8 va = ld32_8al(&vtp[(ds * 32 + lo) * 72 + hi * 32]);
            ctx[ds] = mfma64(va, pfr, ctx[ds]);
        }
        lacc = mfma64(ones, pfr, lacc);
        __builtin_amdgcn_s_setprio(0);

        asm volatile("s_waitcnt vmcnt(8)" ::: "memory");
        __builtin_amdgcn_sched_barrier(0);
        write_k(wbuf, kwr);
        write_vt(wbuf, vwr);
        asm volatile("s_waitcnt lgkmcnt(0)" ::: "memory");
        __builtin_amdgcn_s_barrier();
        __builtin_amdgcn_sched_barrier(0);
    };

    // prologue
    load_k(kA, 0);
    load_v(vA, 0);
    load_k(kB, 1);
    load_v(vB, 1);
    asm volatile("s_waitcnt vmcnt(8)" ::: "memory");
    __builtin_amdgcn_sched_barrier(0);
    write_k(0, kA);
    write_vt(0, vA);
    asm volatile("s_waitcnt lgkmcnt(0)" ::: "memory");
    __builtin_amdgcn_s_barrier();
    __builtin_amdgcn_sched_barrier(0);

    for (int it2 = 0; it2 < 16; ++it2) {
        body(it2 * 2,     &Kb[0][0], &Vt[0][0], kA, vA, kB, vB, 1);
        body(it2 * 2 + 1, &Kb[1][0], &Vt[1][0], kB, vB, kA, vA, 0);
    }

    // ---- epilogue: 1/(16 l), per-wave LDS bounce, coalesced bf16 write ----
    __bf16* sc = (__bf16*)&Kb[0][0] + w * 4096;
    float inv = 1.f / (16.f * lacc[0]);
    #pragma unroll
    for (int ds = 0; ds < 4; ++ds) {
        #pragma unroll
        for (int g = 0; g < 4; ++g) {
            #pragma unroll
            for (int h2 = 0; h2 < 2; ++h2) {
                int r = g * 4 + h2 * 2;
                unsigned pv = pk2(ctx[ds][r] * inv, ctx[ds][r + 1] * inv);
                int d = ds * 32 + (r & 3) + 8 * (r >> 2) + 4 * hi;
                *(unsigned*)&sc[lo * 128 + (((d >> 3) ^ (lo & 7)) << 3) + (d & 7)] = pv;
            }
        }
    }
    {
        int b = bh >> 3, h = bh & 7;
        int qq = lane >> 1, halfd = lane & 1;
        int srow = q0 + w * 32 + qq;
        #pragma unroll
        for (int j = 0; j < 8; ++j) {
            int d8 = halfd * 8 + j;
            bf16x8 vv = *(const bf16x8*)&sc[qq * 128 + ((d8 ^ (qq & 7)) << 3)];
            *(bf16x8*)&ctxg[((size_t)(b * S_ + srow)) * 1024 + h * 128 + d8 * 8] = vv;
        }
    }
}

// ------- out = LN(ctx @ qlin^T + qlin_b + Q); 4 waves split K, wave0 finishes -------
__global__ __launch_bounds__(256) void k_out(const float* Qin, const float* qlin_b,
                                             const float* ln_g, const float* ln_b,
                                             char* ws, float* out) {
    __shared__ f32x16 red[3][4][64];
    int t = threadIdx.x, w = t >> 6, l64 = t & 63;
    int lo = l64 & 31, hi = l64 >> 5;
    int m0 = blockIdx.x * 32;
    const __bf16* ctx = (const __bf16*)(ws + WS_CTX);
    const __bf16* qlb = (const __bf16*)(ws + WS_QLIN);
    f32x16 acc[4];
    #pragma unroll
    for (int g = 0; g < 4; ++g)
        #pragma unroll
        for (int i = 0; i < 16; ++i) acc[g][i] = 0.f;
    const __bf16* arow = ctx + (size_t)(m0 + lo) * 1024 + w * 256;
    #pragma unroll
    for (int ks = 0; ks < 16; ++ks) {
        int kb = ks * 16 + hi * 8;
        bf16x8 af = *(const bf16x8*)(arow + kb);
        int ksg = w * 16 + ks;
        #pragma unroll
        for (int g = 0; g < 4; ++g) {
            bf16x8 bf = *(const bf16x8*)&qlb[((size_t)g * 128 + ksg * 2 + hi) * 256 + lo * 8];
            acc[g] = __builtin_amdgcn_mfma_f32_32x32x16_bf16(af, bf, acc[g], 0, 0, 0);
        }
    }
    if (w > 0) {
        #pragma unroll
        for (int g = 0; g < 4; ++g) red[w - 1][g][l64] = acc[g];
    }
    __syncthreads();
    if (w > 0) return;
    #pragma unroll
    for (int v = 0; v < 3; ++v)
        #pragma unroll
        for (int g = 0; g < 4; ++g) {
            f32x16 o = red[v][g][l64];
            #pragma unroll
            for (int i = 0; i < 16; ++i) acc[g][i] += o[i];
        }
    float gb[4], bb[4], qb[4];
    #pragma unroll
    for (int g = 0; g < 4; ++g) {
        int n = g * 32 + lo;
        gb[g] = ln_g[n]; bb[g] = ln_b[n]; qb[g] = qlin_b[n];
    }
    const float* qp = Qin + (size_t)(m0 + 4 * hi) * 128;
    float* op = out + (size_t)(m0 + 4 * hi) * 128;
    #pragma unroll
    for (int r = 0; r < 16; ++r) {
        int ro = ((r & 3) + 8 * (r >> 2)) * 128;
        float x[4];
        float sum = 0.f;
        #pragma unroll
        for (int g = 0; g < 4; ++g) {
            x[g] = acc[g][r] + qb[g] + qp[ro + g * 32 + lo];
            sum += x[g];
        }
        sum += __shfl_xor(sum, 1);
        sum += __shfl_xor(sum, 2);
        sum += __shfl_xor(sum, 4);
        sum += __shfl_xor(sum, 8);
        sum += __shfl_xor(sum, 16);
        float mean = sum * (1.f / 128.f);
        float sq = 0.f;
        #pragma unroll
        for (int g = 0; g < 4; ++g) {
            float d = x[g] - mean;
            sq += d * d;
        }
        sq += __shfl_xor(sq, 1);
        sq += __shfl_xor(sq, 2);
        sq += __shfl_xor(sq, 4);
        sq += __shfl_xor(sq, 8);
        sq += __shfl_xor(sq, 16);
        float rstd = rsqrtf(sq * (1.f / 128.f) + 1e-5f);
        #pragma unroll
        for (int g = 0; g < 4; ++g)
            op[ro + g * 32 + lo] = (x[g] - mean) * rstd * gb[g] + bb[g];
    }
}

extern "C" void kernel_launch(void* const* d_in, const int* in_sizes, int n_in,
                              void* d_out, int out_size, void* d_ws, size_t ws_size,
                              hipStream_t stream) {
    (void)in_sizes; (void)n_in; (void)out_size; (void)ws_size;
    const float* Q    = (const float*)d_in[0];
    const float* K    = (const float*)d_in[1];
    const float* V    = (const float*)d_in[2];
    const float* QP   = (const float*)d_in[3];
    const float* KP   = (const float*)d_in[4];
    const float* WQw  = (const float*)d_in[6];
    const float* WQb  = (const float*)d_in[7];
    const float* WKw  = (const float*)d_in[8];
    const float* WKb  = (const float*)d_in[9];
    const float* WVw  = (const float*)d_in[10];
    const float* WVb  = (const float*)d_in[11];
    const float* WQPw = (const float*)d_in[12];
    const float* WQPb = (const float*)d_in[13];
    const float* WKPw = (const float*)d_in[14];
    const float* WKPb = (const float*)d_in[15];
    const float* qlw  = (const float*)d_in[18];
    const float* qlb  = (const float*)d_in[19];
    const float* vlw  = (const float*)d_in[20];
    const float* vlb  = (const float*)d_in[21];
    const float* lng  = (const float*)d_in[22];
    const float* lnb  = (const float*)d_in[23];
    char* ws = (char*)d_ws;
    float* out = (float*)d_out;

    k_prep<<<3460, 256, 0, stream>>>(WQw, WKw, WVw, WQPw, WKPw, qlw, vlw, WVb, vlb,
                                     Q, K, V, QP, KP, ws);
    k_proj<<<2624, 256, 0, stream>>>(WQb, WKb, WVb, WQPb, WKPb, ws, out);
    k_attn<<<512, 256, 0, stream>>>(ws);
    k_out<<<256, 256, 0, stream>>>(Q, qlb, lng, lnb, ws, out);
}